// Round 2
// baseline (542.489 us; speedup 1.0000x reference)
//
#include <hip/hip_runtime.h>

typedef __attribute__((ext_vector_type(8))) short short8;
typedef __attribute__((ext_vector_type(4))) float f32x4;

#define SEQ 2048
#define BATCH 64
#define HID 512
#define ATT 512
#define SPB 8   // s-values per persistent block (grid = SEQ/SPB = 256)
#define DPF 2   // b-frag register prefetch depth (L2-resident, ~200-300cyc)

__device__ __forceinline__ unsigned short f2bf(float f) {
  unsigned u = __float_as_uint(f);
  u += 0x7fffu + ((u >> 16) & 1u);   // round-to-nearest-even
  return (unsigned short)(u >> 16);
}
__device__ __forceinline__ float bf2f(unsigned short h) {
  return __uint_as_float(((unsigned)h) << 16);
}

// Pre-kernel: blocks 0..63 compute dec_att rows (fp32, b_t folded); blocks 64..127 convert W_s -> bf16.
__global__ void bahdanau_pre(const float* __restrict__ dec_out,
                             const float* __restrict__ W_t,
                             const float* __restrict__ b_t,
                             const float* __restrict__ W_s,
                             unsigned short* __restrict__ wsb,
                             float* __restrict__ dec_att) {
  if (blockIdx.x < 64) {
    const int b = blockIdx.x;
    __shared__ float drow[HID];
    for (int i = threadIdx.x; i < HID; i += 256) drow[i] = dec_out[b * HID + i];
    __syncthreads();
    for (int a = threadIdx.x; a < ATT; a += 256) {
      const float4* wr = (const float4*)(W_t + (size_t)a * HID);
      float s0 = 0.f, s1 = 0.f, s2 = 0.f, s3 = 0.f;
#pragma unroll 4
      for (int j = 0; j < HID / 4; ++j) {
        float4 w = wr[j];
        s0 = fmaf(w.x, drow[4 * j + 0], s0);
        s1 = fmaf(w.y, drow[4 * j + 1], s1);
        s2 = fmaf(w.z, drow[4 * j + 2], s2);
        s3 = fmaf(w.w, drow[4 * j + 3], s3);
      }
      dec_att[b * ATT + a] = (s0 + s1) + (s2 + s3) + b_t[a];
    }
  } else {
    const int cb = blockIdx.x - 64;
    const float4* src = (const float4*)W_s;
#pragma unroll
    for (int i = 0; i < 4; ++i) {
      int idx = cb * 1024 + i * 256 + threadIdx.x;
      float4 v = src[idx];
      ushort4 o;
      o.x = f2bf(v.x); o.y = f2bf(v.y); o.z = f2bf(v.z); o.w = f2bf(v.w);
      ((ushort4*)wsb)[idx] = o;
    }
  }
}

// Persistent main: grid 256 x 512thr. Block p handles s = p*8..p*8+7.
// Per s: A(s) was loaded to 64 staging VGPRs during compute(s-1) (barrier-free
// region -> fine-grained vmcnt, no vmcnt(0) drain until it has had ~13k cyc).
// cvt->LDS (single buffer, q-stride padded 65), 2 barriers per s, then a
// barrier-free compute phase: 16 K-steps of ds_read + MFMA + depth-2 B prefetch
// + next-s A load issue. Epilogue: fused tanh + v_a dot, dec_att from LDS bf16.
__global__ __launch_bounds__(512, 2)
void bahdanau_main(const float* __restrict__ enc,
                   const unsigned short* __restrict__ wsb,
                   const float* __restrict__ dec_att,
                   const float* __restrict__ v_a,
                   float* __restrict__ out) {
  // A element (row, k): kk=k>>5, qk=(k>>3)&3, j=k&7 -> Albuf[((kk*4+qk)*65 + row)*8 + j]
  __shared__ __align__(16) unsigned short Albuf[64 * 65 * 8];   // 66560 B
  __shared__ __align__(16) unsigned short decl[64 * 520];       // 66560 B, row stride 520 (bank-spread)
  __shared__ float partial[512];                                // 2 KB  -> total 135 KB, 1 block/CU

  const int tid  = threadIdx.x;
  const int wave = tid >> 6;
  const int lane = tid & 63;
  const int c = lane & 15;          // MFMA frag index / D column
  const int q = lane >> 4;          // quad
  const int n0 = wave * 64;
  const int s0 = blockIdx.x * SPB;

  // ---- fill decl: dec_att fp32 (L2-warm from pre-kernel) -> bf16 LDS ----
  {
    const float4* dsrc = (const float4*)dec_att;
#pragma unroll
    for (int i = 0; i < 16; ++i) {
      int idx = i * 512 + tid;            // float4 index over 64x512
      float4 v = dsrc[idx];
      int e = idx * 4;
      int row = e >> 9, col = e & 511;
      ushort4 o;
      o.x = f2bf(v.x); o.y = f2bf(v.y); o.z = f2bf(v.z); o.w = f2bf(v.w);
      *(ushort4*)&decl[row * 520 + col] = o;
    }
  }

  // ---- A staging mapping: thread t -> (row=t>>3, k = (t&7)*4 + 32*kk) ----
  const int srow = tid >> 3;
  const int skc  = (tid & 7) * 4;
  const int ldst = (((skc >> 3) & 3) * 65 + srow) * 8 + (skc & 7);   // + kk*2080
  const float* gbase = enc + ((size_t)s0 * 64 + srow) * HID + skc;

  float4 stg[16];
#pragma unroll
  for (int kk = 0; kk < 16; ++kk) stg[kk] = *(const float4*)(gbase + kk * 32);

  // b-frag base: lane reads wsb[(n0 + nt*16 + c)*512 + kk*32 + q*8 ..+7]
  const unsigned short* bsrc = wsb + (size_t)(n0 + c) * HID + q * 8;

  float va[4];
#pragma unroll
  for (int nt = 0; nt < 4; ++nt) va[nt] = v_a[n0 + nt * 16 + c];

  for (int si = 0; si < SPB; ++si) {
    __syncthreads();   // B1: stg(s) drained, Albuf free, partial(s-1) ready

    if (si > 0 && tid < 64) {
      float sum = 0.f;
#pragma unroll
      for (int w = 0; w < 8; ++w) sum += partial[w * 64 + tid];
      out[(size_t)tid * SEQ + (s0 + si - 1)] = sum;
    }

    // convert + write A(s) into LDS
#pragma unroll
    for (int kk = 0; kk < 16; ++kk) {
      ushort4 o;
      o.x = f2bf(stg[kk].x); o.y = f2bf(stg[kk].y);
      o.z = f2bf(stg[kk].z); o.w = f2bf(stg[kk].w);
      *(ushort4*)&Albuf[kk * 2080 + ldst] = o;
    }

    __syncthreads();   // B2: Albuf ready

    const float* gnext = gbase + (size_t)(si + 1) * (64 * HID);
    const bool more = (si + 1 < SPB);

    // B prefetch, depth DPF
    short8 bp[DPF][4];
#pragma unroll
    for (int d = 0; d < DPF; ++d)
#pragma unroll
      for (int nt = 0; nt < 4; ++nt)
        bp[d][nt] = *(const short8*)(bsrc + (size_t)nt * 16 * HID + d * 32);

    f32x4 acc[4][4] = {};   // [mt][nt]

#pragma unroll
    for (int kk = 0; kk < 16; ++kk) {
      const unsigned short* ab = &Albuf[kk * 2080 + (q * 65 + c) * 8];
      short8 a4[4];
#pragma unroll
      for (int mt = 0; mt < 4; ++mt)
        a4[mt] = *(const short8*)(ab + mt * 16 * 8);

#pragma unroll
      for (int mt = 0; mt < 4; ++mt)
#pragma unroll
        for (int nt = 0; nt < 4; ++nt)
          acc[mt][nt] = __builtin_amdgcn_mfma_f32_16x16x32_bf16(a4[mt], bp[kk % DPF][nt], acc[mt][nt], 0, 0, 0);

      if (kk + DPF < 16) {
#pragma unroll
        for (int nt = 0; nt < 4; ++nt)
          bp[kk % DPF][nt] = *(const short8*)(bsrc + (size_t)nt * 16 * HID + (kk + DPF) * 32);
      }
      // spread next-s A loads through the barrier-free region
      if (more) stg[kk] = *(const float4*)(gnext + kk * 32);
    }

    // ---- epilogue: x = acc + dec; score += v_a * tanh(x) ----
    float rowsum[4][4];
#pragma unroll
    for (int mt = 0; mt < 4; ++mt) {
#pragma unroll
      for (int r = 0; r < 4; ++r) {
        const int ml = mt * 16 + q * 4 + r;           // batch index b
        float sum = 0.f;
#pragma unroll
        for (int nt = 0; nt < 4; ++nt) {
          const int n = n0 + nt * 16 + c;
          float x = acc[mt][nt][r] + bf2f(decl[ml * 520 + n]);
          float e = __builtin_amdgcn_exp2f(x * 2.8853900817779268f);
          float t = 1.f - 2.f * __builtin_amdgcn_rcpf(e + 1.f);
          sum = fmaf(va[nt], t, sum);
        }
        rowsum[mt][r] = sum;
      }
    }

#pragma unroll
    for (int off = 1; off < 16; off <<= 1) {
#pragma unroll
      for (int mt = 0; mt < 4; ++mt)
#pragma unroll
        for (int r = 0; r < 4; ++r)
          rowsum[mt][r] += __shfl_xor(rowsum[mt][r], off, 64);
    }

    if (c == 0) {
#pragma unroll
      for (int mt = 0; mt < 4; ++mt)
#pragma unroll
        for (int r = 0; r < 4; ++r)
          partial[wave * 64 + mt * 16 + q * 4 + r] = rowsum[mt][r];
    }
  }

  __syncthreads();
  if (tid < 64) {
    float sum = 0.f;
#pragma unroll
    for (int w = 0; w < 8; ++w) sum += partial[w * 64 + tid];
    out[(size_t)tid * SEQ + (s0 + SPB - 1)] = sum;
  }
}

extern "C" void kernel_launch(void* const* d_in, const int* in_sizes, int n_in,
                              void* d_out, int out_size, void* d_ws, size_t ws_size,
                              hipStream_t stream) {
  const float* dec_out = (const float*)d_in[0];   // (64, 512)
  const float* enc     = (const float*)d_in[1];   // (2048, 64, 512)
  const float* W_s     = (const float*)d_in[2];   // (512, 512)
  const float* W_t     = (const float*)d_in[3];   // (512, 512)
  const float* b_t     = (const float*)d_in[4];   // (512,)
  const float* v_a     = (const float*)d_in[5];   // (512,)
  float* out = (float*)d_out;                     // (64, 2048)

  unsigned short* wsb = (unsigned short*)d_ws;                      // 512 KB: W_s bf16
  float* dec_att = (float*)((char*)d_ws + (size_t)ATT * HID * 2);   // 128 KB: dec_att fp32

  bahdanau_pre<<<128, 256, 0, stream>>>(dec_out, W_t, b_t, W_s, wsb, dec_att);
  bahdanau_main<<<SEQ / SPB, 512, 0, stream>>>(enc, wsb, dec_att, v_a, out);
}

// Round 3
// 523.628 us; speedup vs baseline: 1.0360x; 1.0360x over previous
//
#include <hip/hip_runtime.h>

typedef __attribute__((ext_vector_type(8))) short short8;
typedef __attribute__((ext_vector_type(4))) float f32x4;

#define SEQ 2048
#define BATCH 64
#define HID 512
#define ATT 512
#define SPB 8   // s-tiles per persistent block (grid = 256 = 1 block/CU)

__device__ __forceinline__ unsigned short f2bf(float f) {
  unsigned u = __float_as_uint(f);
  u += 0x7fffu + ((u >> 16) & 1u);   // round-to-nearest-even
  return (unsigned short)(u >> 16);
}

// Pre-kernel: blocks 0..63 compute decT[a][b] = (W_t@dec_out[b] + b_t)[a] (TRANSPOSED, fp32);
// blocks 64..127 convert W_s -> bf16.
__global__ void bahdanau_pre(const float* __restrict__ dec_out,
                             const float* __restrict__ W_t,
                             const float* __restrict__ b_t,
                             const float* __restrict__ W_s,
                             unsigned short* __restrict__ wsb,
                             float* __restrict__ decT) {
  if (blockIdx.x < 64) {
    const int b = blockIdx.x;
    __shared__ float drow[HID];
    for (int i = threadIdx.x; i < HID; i += 256) drow[i] = dec_out[b * HID + i];
    __syncthreads();
    for (int a = threadIdx.x; a < ATT; a += 256) {
      const float4* wr = (const float4*)(W_t + (size_t)a * HID);
      float s0 = 0.f, s1 = 0.f, s2 = 0.f, s3 = 0.f;
#pragma unroll 4
      for (int j = 0; j < HID / 4; ++j) {
        float4 w = wr[j];
        s0 = fmaf(w.x, drow[4 * j + 0], s0);
        s1 = fmaf(w.y, drow[4 * j + 1], s1);
        s2 = fmaf(w.z, drow[4 * j + 2], s2);
        s3 = fmaf(w.w, drow[4 * j + 3], s3);
      }
      decT[a * BATCH + b] = (s0 + s1) + (s2 + s3) + b_t[a];
    }
  } else {
    const int cb = blockIdx.x - 64;
    const float4* src = (const float4*)W_s;
#pragma unroll
    for (int i = 0; i < 4; ++i) {
      int idx = cb * 1024 + i * 256 + threadIdx.x;
      float4 v = src[idx];
      ushort4 o;
      o.x = f2bf(v.x); o.y = f2bf(v.y); o.z = f2bf(v.z); o.w = f2bf(v.w);
      ((ushort4*)wsb)[idx] = o;
    }
  }
}

// Persistent main: 256 blocks x 512 thr, block handles 8 s-tiles.
// Double-buffered A-LDS (bf16, padded), ONE barrier per s-tile.
// Staging: rolling 4-deep float4 pipeline per thread (16 VGPRs), loads trapped in a
// #pragma unroll 1 loop so they cannot be hoisted (spill!) and vmcnt never drains mid-tile.
// acc initialized from decT (dec_att folded in); b-frags depth-2 from L2.
__global__ __launch_bounds__(512, 2)
void bahdanau_main(const float* __restrict__ enc,
                   const unsigned short* __restrict__ wsb,
                   const float* __restrict__ decT,
                   const float* __restrict__ v_a,
                   float* __restrict__ out) {
  // A chunk kk (64 rows x 32 k): element (row, k=qk*8+j) at [kk*2080 + (qk*65+row)*8 + j]
  __shared__ __align__(16) unsigned short Albuf[2][16 * 4 * 65 * 8];  // 2 x 66560 B
  __shared__ float partial[2][512];                                   // 4 KB -> total 137216 B

  const int tid  = threadIdx.x;
  const int wave = tid >> 6;
  const int lane = tid & 63;
  const int c = lane & 15;
  const int q = lane >> 4;
  const int n0 = wave * 64;
  const int s0 = blockIdx.x * SPB;

  // staging map: thread t -> (row = t>>3, floats skc..skc+3 of each 32-k chunk)
  const int srow = tid >> 3;
  const int skc  = (tid & 7) * 4;
  const int ldst = (((skc >> 3) & 3) * 65 + srow) * 8 + (skc & 7);
  const float* gbase = enc + ((size_t)s0 * 64 + srow) * HID + skc;

  const unsigned short* bsrc = wsb + (size_t)(n0 + c) * HID + q * 8;

  float va[4];
#pragma unroll
  for (int nt = 0; nt < 4; ++nt) va[nt] = v_a[n0 + nt * 16 + c];

  // ---- prologue: stage tile 0 into Albuf[0], 4 chunks per group (depth-limited) ----
#pragma unroll 1
  for (int g = 0; g < 4; ++g) {
    float4 v[4];
#pragma unroll
    for (int u = 0; u < 4; ++u) v[u] = *(const float4*)(gbase + (g * 4 + u) * 32);
#pragma unroll
    for (int u = 0; u < 4; ++u) {
      ushort4 o;
      o.x = f2bf(v[u].x); o.y = f2bf(v[u].y); o.z = f2bf(v[u].z); o.w = f2bf(v[u].w);
      *(ushort4*)&Albuf[0][(g * 4 + u) * 2080 + ldst] = o;
    }
  }
  __syncthreads();

#pragma unroll 1
  for (int si = 0; si < SPB; ++si) {
    unsigned short* Acur = Albuf[si & 1];
    unsigned short* Anxt = Albuf[(si & 1) ^ 1];
    const bool more = (si + 1 < SPB);
    const float* gnext = gbase + (size_t)(si + 1) * (64 * HID);

    // acc init = dec_att (fp32 from decT, L2-warm): acc[mt][nt][r] = decT[n][mt*16+q*4+r]
    f32x4 acc[4][4];
#pragma unroll
    for (int nt = 0; nt < 4; ++nt)
#pragma unroll
      for (int mt = 0; mt < 4; ++mt)
        acc[mt][nt] = *(const f32x4*)(decT + (size_t)(n0 + nt * 16 + c) * 64 + mt * 16 + q * 4);

    // b-frag prefetch, depth 2
    short8 bp[2][4];
#pragma unroll
    for (int d = 0; d < 2; ++d)
#pragma unroll
      for (int nt = 0; nt < 4; ++nt)
        bp[d][nt] = *(const short8*)(bsrc + nt * 16 * HID + d * 32);

    // staging pipeline preload: chunks 0..3 of next tile
    float4 stg[4];
    if (more) {
#pragma unroll
      for (int u = 0; u < 4; ++u) stg[u] = *(const float4*)(gnext + u * 32);
    }

    // ---- K-loop: 16 steps, no barriers; loads depth-trapped by unroll-1 g loop ----
#pragma unroll 1
    for (int g = 0; g < 4; ++g) {
#pragma unroll
      for (int u = 0; u < 4; ++u) {
        const int kk = g * 4 + u;

        const unsigned short* ab = &Acur[kk * 2080 + (q * 65 + c) * 8];
        short8 a4[4];
#pragma unroll
        for (int mt = 0; mt < 4; ++mt)
          a4[mt] = *(const short8*)(ab + mt * 128);

#pragma unroll
        for (int mt = 0; mt < 4; ++mt)
#pragma unroll
          for (int nt = 0; nt < 4; ++nt)
            acc[mt][nt] = __builtin_amdgcn_mfma_f32_16x16x32_bf16(a4[mt], bp[u & 1][nt], acc[mt][nt], 0, 0, 0);

        // b prefetch for kk+2 (kk=14,15 overread ~64B into decT region: harmless, unused)
#pragma unroll
        for (int nt = 0; nt < 4; ++nt)
          bp[u & 1][nt] = *(const short8*)(bsrc + nt * 16 * HID + (kk + 2) * 32);

        if (more) {
          // write chunk kk of next tile, then reload slot with chunk kk+4
          ushort4 o;
          o.x = f2bf(stg[u].x); o.y = f2bf(stg[u].y);
          o.z = f2bf(stg[u].z); o.w = f2bf(stg[u].w);
          *(ushort4*)&Anxt[kk * 2080 + ldst] = o;
          if (kk < 12) stg[u] = *(const float4*)(gnext + (kk + 4) * 32);
        }
      }
    }

    // ---- epilogue: score += v_a * tanh(acc) (dec already folded in) ----
    float rowsum[4][4];
#pragma unroll
    for (int mt = 0; mt < 4; ++mt) {
#pragma unroll
      for (int r = 0; r < 4; ++r) {
        float sum = 0.f;
#pragma unroll
        for (int nt = 0; nt < 4; ++nt) {
          float x = acc[mt][nt][r];
          float e = __builtin_amdgcn_exp2f(x * 2.8853900817779268f);
          float t = 1.f - 2.f * __builtin_amdgcn_rcpf(e + 1.f);
          sum = fmaf(va[nt], t, sum);
        }
        rowsum[mt][r] = sum;
      }
    }

#pragma unroll
    for (int off = 1; off < 16; off <<= 1) {
#pragma unroll
      for (int mt = 0; mt < 4; ++mt)
#pragma unroll
        for (int r = 0; r < 4; ++r)
          rowsum[mt][r] += __shfl_xor(rowsum[mt][r], off, 64);
    }

    if (c == 0) {
#pragma unroll
      for (int mt = 0; mt < 4; ++mt)
#pragma unroll
        for (int r = 0; r < 4; ++r)
          partial[si & 1][wave * 64 + mt * 16 + q * 4 + r] = rowsum[mt][r];
    }

    __syncthreads();   // the ONE barrier: Anxt writes + partial ready; nothing in flight

    if (tid < 64) {
      float sum = 0.f;
#pragma unroll
      for (int w = 0; w < 8; ++w) sum += partial[si & 1][w * 64 + tid];
      out[(size_t)tid * SEQ + s0 + si] = sum;
    }
  }
}

extern "C" void kernel_launch(void* const* d_in, const int* in_sizes, int n_in,
                              void* d_out, int out_size, void* d_ws, size_t ws_size,
                              hipStream_t stream) {
  const float* dec_out = (const float*)d_in[0];   // (64, 512)
  const float* enc     = (const float*)d_in[1];   // (2048, 64, 512)
  const float* W_s     = (const float*)d_in[2];   // (512, 512)
  const float* W_t     = (const float*)d_in[3];   // (512, 512)
  const float* b_t     = (const float*)d_in[4];   // (512,)
  const float* v_a     = (const float*)d_in[5];   // (512,)
  float* out = (float*)d_out;                     // (64, 2048)

  unsigned short* wsb = (unsigned short*)d_ws;                     // 512 KB: W_s bf16
  float* decT = (float*)((char*)d_ws + (size_t)ATT * HID * 2);     // 128 KB: dec_att^T fp32

  bahdanau_pre<<<128, 256, 0, stream>>>(dec_out, W_t, b_t, W_s, wsb, decT);
  bahdanau_main<<<SEQ / SPB, 512, 0, stream>>>(enc, wsb, decT, v_a, out);
}